// Round 13
// baseline (160.834 us; speedup 1.0000x reference)
//
#include <hip/hip_runtime.h>
#include <hip/hip_bf16.h>

// Problem constants
#define B_   128
#define J_   2048
#define N_   32
#define D_   16
#define NJC  32       // j-chunks (64 j each) for capsA s-partials

typedef __attribute__((ext_vector_type(8))) short short8b;   // 8 bf16 (4 VGPRs)
typedef __attribute__((ext_vector_type(4))) float f32x4;     // 16x16 MFMA acc
typedef __attribute__((ext_vector_type(16))) float f32x16;   // 32x32 MFMA acc

__device__ inline short bf16s(float f) {
    union { __hip_bfloat16 h; short s; } u;
    u.h = __float2bfloat16(f);
    return u.s;
}

// Workspace layout (float offsets), ws_size ~256 MiB:
//  xT     [0, 2097152)             xT[(j*128+b)*8 + p]          8 MB fp32
//  blogT  [2097152, 6291456)       blogT[(n*J+j)*128 + b]     16 MB bf16
//  cT     [6291456, 10485760)      cT[(n*J+j)*128 + b]        16 MB bf16
//  s_part [10485760, 12582912)     [jc][b*512+n*16+d]          8 MB fp32
//  oT     [12582912, 12615680)     oT[(n*128+b)*16 + d]      128 KB bf16
//  Wbf    [12615680, 16809984)     W bf16, layout [n][j][d][p] 16 MB
//  Wt     [16809984, 21004288)     W bf16, layout [n][j][p][d] 16 MB
// total 84 MB

// ---------------------------------------------------------------------------
// W: one-time W fp32 -> bf16 in two layouts (Wbf straight, Wt d<->p transposed)
// ---------------------------------------------------------------------------
__global__ __launch_bounds__(256) void capsW(const float* __restrict__ W,
                                             __hip_bfloat16* __restrict__ Wbf,
                                             __hip_bfloat16* __restrict__ Wt) {
    __shared__ float lds[16 * 132];
    const int t = threadIdx.x;
    const size_t base = (size_t)blockIdx.x * 2048;   // 16 rows x 128 elems
    const int r  = t >> 4;                           // row 0..15
    const int e0 = (t & 15) * 8;                     // elem offset within row

    float4 a = *(const float4*)(W + base + t * 8);
    float4 b = *(const float4*)(W + base + t * 8 + 4);
    short8b w8;
    w8[0]=bf16s(a.x); w8[1]=bf16s(a.y); w8[2]=bf16s(a.z); w8[3]=bf16s(a.w);
    w8[4]=bf16s(b.x); w8[5]=bf16s(b.y); w8[6]=bf16s(b.z); w8[7]=bf16s(b.w);
    *(short8b*)((short*)Wbf + base + t * 8) = w8;
    *(float4*)&lds[r * 132 + e0]     = a;
    *(float4*)&lds[r * 132 + e0 + 4] = b;
    __syncthreads();

    short8b o8;
    #pragma unroll
    for (int k = 0; k < 8; ++k) {
        int q = e0 + k;                 // Wt within-row index = p*16 + d
        int p = q >> 4, d = q & 15;
        o8[k] = bf16s(lds[r * 132 + d * 8 + p]);
    }
    *(short8b*)((short*)Wt + base + t * 8) = o8;
}

// ---------------------------------------------------------------------------
// T: xT[(j*128+b)*8+p] = x[b][j][p]   (LDS tile transpose)
// ---------------------------------------------------------------------------
__global__ __launch_bounds__(256) void capsT(const float* __restrict__ x,
                                             float* __restrict__ xT) {
    __shared__ float tile[32 * 260 + 4];
    const int t  = threadIdx.x;
    const int jt = blockIdx.x & 63;
    const int bt = blockIdx.x >> 6;
    const int j0 = jt * 32, b0 = bt * 32;

    for (int idx = t; idx < 2048; idx += 256) {
        int bl = idx >> 6, f4 = idx & 63;
        float4 v = *(const float4*)(x + (size_t)(b0 + bl) * 16384 + j0 * 8 + f4 * 4);
        *(float4*)&tile[bl * 260 + f4 * 4] = v;
    }
    __syncthreads();
    for (int idx = t; idx < 2048; idx += 256) {
        int jj = idx >> 6, f4o = idx & 63;
        int bl = f4o >> 1, po = (f4o & 1) * 4;
        float4 v = *(const float4*)&tile[bl * 260 + jj * 8 + po];
        *(float4*)(xT + ((size_t)(j0 + jj) * 128 + b0 + bl) * 8 + po) = v;
    }
}

// ---------------------------------------------------------------------------
// A (MFMA, unchanged from round 12): s_part[jc][b,n,d] = y(b,K) x W(K,d)
// ---------------------------------------------------------------------------
__global__ __launch_bounds__(256) void capsA(const __hip_bfloat16* __restrict__ Wbf,
                                             const float* __restrict__ xT,
                                             const __hip_bfloat16* __restrict__ cT,
                                             float* __restrict__ s_part,
                                             int mode) {
    const int t     = threadIdx.x;
    const int lane  = t & 63;
    const int i     = blockIdx.x;                    // 0..1023
    const int jc    = (i & 7) + 8 * (i >> 8);        // 0..31 (XCD-grouped)
    const int n     = (i >> 3) & 31;
    const int wv    = t >> 6;                        // 0..3
    const int colid = lane & 15;                     // d for B / b_low for A
    const int kgrp  = lane >> 4;                     // 0..3 -> j within K-step

    const int b0 = wv * 32 + colid;                  // A row, tile 0
    const int b1 = b0 + 16;                          // A row, tile 1

    f32x4 acc0 = {0.f, 0.f, 0.f, 0.f};
    f32x4 acc1 = {0.f, 0.f, 0.f, 0.f};

    for (int ks = 0; ks < 16; ++ks) {
        const int j = jc * 64 + ks * 4 + kgrp;       // per-lane j

        short8b bfrag = *(const short8b*)((const short*)Wbf
                          + (((size_t)n * J_ + j) * 16 + colid) * 8);

        float c0 = 1.0f / 32.0f, c1 = 1.0f / 32.0f;
        if (mode) {
            c0 = __bfloat162float(cT[((size_t)n * J_ + j) * B_ + b0]);
            c1 = __bfloat162float(cT[((size_t)n * J_ + j) * B_ + b1]);
        }

        const float4* xp0 = (const float4*)(xT + ((size_t)j * 128 + b0) * 8);
        float4 xa = xp0[0], xb = xp0[1];
        short8b afrag0;
        afrag0[0] = bf16s(xa.x * c0); afrag0[1] = bf16s(xa.y * c0);
        afrag0[2] = bf16s(xa.z * c0); afrag0[3] = bf16s(xa.w * c0);
        afrag0[4] = bf16s(xb.x * c0); afrag0[5] = bf16s(xb.y * c0);
        afrag0[6] = bf16s(xb.z * c0); afrag0[7] = bf16s(xb.w * c0);

        const float4* xp1 = (const float4*)(xT + ((size_t)j * 128 + b1) * 8);
        float4 xe = xp1[0], xf = xp1[1];
        short8b afrag1;
        afrag1[0] = bf16s(xe.x * c1); afrag1[1] = bf16s(xe.y * c1);
        afrag1[2] = bf16s(xe.z * c1); afrag1[3] = bf16s(xe.w * c1);
        afrag1[4] = bf16s(xf.x * c1); afrag1[5] = bf16s(xf.y * c1);
        afrag1[6] = bf16s(xf.z * c1); afrag1[7] = bf16s(xf.w * c1);

        acc0 = __builtin_amdgcn_mfma_f32_16x16x32_bf16(afrag0, bfrag, acc0, 0, 0, 0);
        acc1 = __builtin_amdgcn_mfma_f32_16x16x32_bf16(afrag1, bfrag, acc1, 0, 0, 0);
    }

    float* sdst = s_part + (size_t)jc * (B_ * N_ * D_);
    #pragma unroll
    for (int r = 0; r < 4; ++r) {
        int brow = wv * 32 + kgrp * 4 + r;
        sdst[(size_t)brow * 512 + n * 16 + colid]        = acc0[r];
        sdst[(size_t)(brow + 16) * 512 + n * 16 + colid] = acc1[r];
    }
}

// ---------------------------------------------------------------------------
// R: out[b,n,d] = squash(sum_jc s_part + bias); also emit oT bf16 for capsB
// ---------------------------------------------------------------------------
__global__ __launch_bounds__(256) void capsR(const float* __restrict__ s_part,
                                             const float* __restrict__ bias,
                                             float* __restrict__ out,
                                             __hip_bfloat16* __restrict__ oT) {
    int gid = blockIdx.x * 256 + threadIdx.x;       // 65536: b*512 + n*16 + d
    float sv = bias[gid & 511];
    #pragma unroll
    for (int jc = 0; jc < NJC; ++jc)
        sv += s_part[(size_t)jc * 65536 + gid];
    float sq = sv * sv;
    sq += __shfl_xor(sq, 1);
    sq += __shfl_xor(sq, 2);
    sq += __shfl_xor(sq, 4);
    sq += __shfl_xor(sq, 8);
    float scale = sq / (1.0f + sq) / sqrtf(sq + 1e-7f);
    float ov = scale * sv;
    out[gid] = ov;
    int b = gid >> 9, nd = gid & 511;
    int n = nd >> 4, d = nd & 15;
    oT[((size_t)n * B_ + b) * D_ + d] = __float2bfloat16(ov);
}

// ---------------------------------------------------------------------------
// B (MFMA v7, fused softmax): block = (4 j, 128 b, ALL 32 n), grid 512.
//   Per n: V[(j,p),b]=sum_d Wt*o via mfma_f32_32x32x16_bf16; blog=sum_p V*x.
//   Owner lane (bt=wv, g==jl2>>1) keeps the full 32-n logit vector for its
//   (j,b) in registers (keep[2][32], fully unrolled => static indexing),
//   then computes softmax in-register and writes cT directly. capsD deleted.
//   writeBlog=0 on the last call skips the dead blogT store.
// ---------------------------------------------------------------------------
__global__ __launch_bounds__(256) void capsB(const __hip_bfloat16* __restrict__ Wt,
                                             const float* __restrict__ xT,
                                             const __hip_bfloat16* __restrict__ oT,
                                             __hip_bfloat16* __restrict__ blogT,
                                             __hip_bfloat16* __restrict__ cT,
                                             int accumulate, int writeBlog) {
    const int t    = threadIdx.x;
    const int lane = t & 63;
    const int i    = blockIdx.x;              // 0..511
    const int xcd  = i & 7;
    const int jq   = xcd * 64 + (i >> 3);     // 0..511 (XCD owns 256 j)
    const int j0   = jq * 4;
    const int wv   = t >> 6;                  // 0..3  -> owned b-tile
    const int g    = lane >> 5;               // k-half (d 0-7 / 8-15)
    const int col  = lane & 31;
    const int jl   = col >> 3;                // j within quad (A-row)
    const int p    = col & 7;
    const int b    = wv * 32 + col;           // wave-owned b (race-free)

    // ---- epilogue x operands: own b only, 4 float4 in VGPRs ----
    float4 xv[4];
    #pragma unroll
    for (int jl2 = 0; jl2 < 4; ++jl2)
        xv[jl2] = *(const float4*)(xT + ((size_t)(j0 + jl2) * 128 + b) * 8 + g * 4);

    f32x16 zz;
    #pragma unroll
    for (int q = 0; q < 16; ++q) zz[q] = 0.0f;

    float keep[2][32];                        // full 32-n logits per owned (j,b)

    #pragma unroll
    for (int nn = 0; nn < 32; ++nn) {
        short8b bfrag = *(const short8b*)(oT + ((size_t)nn * B_ + b) * D_ + g * 8);
        short8b afrag = *(const short8b*)((const short*)Wt
                          + (((size_t)nn * J_ + j0 + jl) * 8 + p) * 16 + g * 8);

        f32x16 acc =
            __builtin_amdgcn_mfma_f32_32x32x16_bf16(afrag, bfrag, zz, 0, 0, 0);

        #pragma unroll
        for (int jl2 = 0; jl2 < 4; ++jl2) {
            float4 v = xv[jl2];
            float tt = acc[jl2 * 4 + 0] * v.x
                     + acc[jl2 * 4 + 1] * v.y
                     + acc[jl2 * 4 + 2] * v.z
                     + acc[jl2 * 4 + 3] * v.w;
            tt += __shfl_xor(tt, 32);                // combine p halves
            if (g == (jl2 >> 1)) {                   // owner lane for this j
                size_t a0 = ((size_t)nn * J_ + j0 + jl2) * B_ + b;
                if (accumulate) tt += __bfloat162float(blogT[a0]);
                if (writeBlog)  blogT[a0] = __float2bfloat16(tt);
                keep[jl2 & 1][nn] = tt;              // static idx (unrolled)
            }
        }
    }

    // ---- in-register softmax over n for the two owned j rows ----
    #pragma unroll
    for (int k2 = 0; k2 < 2; ++k2) {
        const int j = j0 + 2 * g + k2;
        float m = keep[k2][0];
        #pragma unroll
        for (int nn = 1; nn < 32; ++nn) m = fmaxf(m, keep[k2][nn]);
        float sum = 0.0f;
        #pragma unroll
        for (int nn = 0; nn < 32; ++nn) {
            float e = __expf(keep[k2][nn] - m);
            keep[k2][nn] = e;
            sum += e;
        }
        float inv = 1.0f / sum;
        #pragma unroll
        for (int nn = 0; nn < 32; ++nn)
            cT[((size_t)nn * J_ + j) * B_ + b] = __float2bfloat16(keep[k2][nn] * inv);
    }
}

// ---------------------------------------------------------------------------
extern "C" void kernel_launch(void* const* d_in, const int* in_sizes, int n_in,
                              void* d_out, int out_size, void* d_ws, size_t ws_size,
                              hipStream_t stream) {
    const float* x    = (const float*)d_in[0];   // [128,2048,8]
    const float* W    = (const float*)d_in[1];   // [32,2048,16,8]
    const float* bias = (const float*)d_in[2];   // [32,16]
    float* out = (float*)d_out;                  // [128,32,16]

    float* ws = (float*)d_ws;
    float*           xT     = ws;                                    // 8 MB
    __hip_bfloat16*  blogT  = (__hip_bfloat16*)(ws + 2097152);       // 16 MB
    __hip_bfloat16*  cT     = (__hip_bfloat16*)(ws + 6291456);       // 16 MB
    float*           s_part = ws + 10485760;                         // 8 MB
    __hip_bfloat16*  oT     = (__hip_bfloat16*)(ws + 12582912);      // 128 KB
    __hip_bfloat16*  Wbf    = (__hip_bfloat16*)(ws + 12615680);      // 16 MB
    __hip_bfloat16*  Wt     = (__hip_bfloat16*)(ws + 16809984);      // 16 MB

    dim3 b256(256);

    capsW<<<dim3(4096), b256, 0, stream>>>(W, Wbf, Wt);
    capsT<<<dim3(256),  b256, 0, stream>>>(x, xT);

    // ---- routing iteration 0 (c uniform) ----
    capsA<<<dim3(1024), b256, 0, stream>>>(Wbf, xT, cT, s_part, 0);
    capsR<<<dim3(256),  b256, 0, stream>>>(s_part, bias, out, oT);
    capsB<<<dim3(512),  b256, 0, stream>>>(Wt, xT, oT, blogT, cT, 0, 1);

    // ---- routing iteration 1 ----
    capsA<<<dim3(1024), b256, 0, stream>>>(Wbf, xT, cT, s_part, 1);
    capsR<<<dim3(256),  b256, 0, stream>>>(s_part, bias, out, oT);
    capsB<<<dim3(512),  b256, 0, stream>>>(Wt, xT, oT, blogT, cT, 1, 0);

    // ---- routing iteration 2 (final) ----
    capsA<<<dim3(1024), b256, 0, stream>>>(Wbf, xT, cT, s_part, 1);
    capsR<<<dim3(256),  b256, 0, stream>>>(s_part, bias, out, oT);
}